// Round 2
// baseline (482.050 us; speedup 1.0000x reference)
//
#include <hip/hip_runtime.h>
#include <hip/hip_bf16.h>

#define NB 262144
#define HH 128
#define WW 16
#define LL 64
#define XRS 66   // x_lds row stride in dwords (132 shorts = 264B, 8B-aligned ops)
#define RRS 20   // reg_lds row stride in dwords (40 shorts = 80B, 16B-aligned reads)

typedef __attribute__((ext_vector_type(8))) short bf16x8;
typedef __attribute__((ext_vector_type(4))) float f32x4;

union FragU { bf16x8 v; uint2 p2[2]; uint4 p4; };

// round-to-nearest-even bf16 pack of two floats (bit-exact vs __float2bfloat16_rn
// for finite values)
__device__ __forceinline__ unsigned int pk_bf16(float a, float b) {
    unsigned int ua = __builtin_bit_cast(unsigned int, a);
    unsigned int ub = __builtin_bit_cast(unsigned int, b);
    ua = (ua + 0x7FFFu + ((ua >> 16) & 1u)) >> 16;
    ub = (ub + 0x7FFFu + ((ub >> 16) & 1u)) >> 16;
    return (ua & 0xFFFFu) | (ub << 16);
}

// kbu[w] = sum_h wd[w][h] * bu[h]  (bias-evolution constant for the bu-elimination trick)
__global__ void kbu_kernel(const float* __restrict__ wd,
                           const float* __restrict__ bu,
                           float* __restrict__ kbu) {
    int c = threadIdx.x;
    if (c < WW) {
        float acc = 0.f;
        for (int h = 0; h < HH; ++h) acc = fmaf(wd[c * HH + h], bu[h], acc);
        kbu[c] = acc;
    }
}

__global__ __launch_bounds__(64, 3)
void proc_kernel(const float* __restrict__ x,
                 const float* __restrict__ program,
                 const float* __restrict__ wd,
                 const float* __restrict__ bd,
                 const float* __restrict__ wu,
                 const float* __restrict__ bu,
                 const float* __restrict__ kbu,
                 float* __restrict__ out)
{
    // per-wave-private LDS scratch (block = 1 wave => no inter-wave hazards)
    __shared__ __align__(16) unsigned int x_lds[16 * XRS];
    __shared__ __align__(16) unsigned int reg_lds[16 * RRS];
    __shared__ __align__(16) float prog_lds[LL * WW];

    const int lane = threadIdx.x;   // 0..63
    const int c = lane & 15;        // batch-col within tile / M-index for A-frags
    const int q = lane >> 4;        // quad group
    const long row = (long)blockIdx.x * 16 + c;

    // stage program (64x16 fp32, 4KB) into LDS: each lane copies 4 float4
    {
        const float4* ps = (const float4*)program;
        float4* pd = (float4*)prog_lds;
        #pragma unroll
        for (int i = 0; i < 4; ++i) pd[lane * 4 + i] = ps[lane * 4 + i];
    }

    // zero reg_lds pad region (k = 16..31 of the up-proj B operand) once
    if (q >= 2) *(uint4*)&reg_lds[c * RRS + q * 4] = make_uint4(0, 0, 0, 0);

    // ---- preload wd A-frags: A[m=w=c][k=h=kc*32+q*8+j], K=128 in 4 chunks
    bf16x8 a_wd[4];
    #pragma unroll
    for (int kc = 0; kc < 4; ++kc) {
        const float* p = wd + c * HH + kc * 32 + q * 8;
        float4 f0 = *(const float4*)p;
        float4 f1 = *(const float4*)(p + 4);
        FragU u;
        u.p2[0] = make_uint2(pk_bf16(f0.x, f0.y), pk_bf16(f0.z, f0.w));
        u.p2[1] = make_uint2(pk_bf16(f1.x, f1.y), pk_bf16(f1.z, f1.w));
        a_wd[kc] = u.v;
    }

    // ---- preload wu A-frags: A[m=h=hc*16+c][k=w=q*8+j], zeros for k>=16 (q>=2)
    bf16x8 a_wu[8];
    #pragma unroll
    for (int hc = 0; hc < 8; ++hc) {
        FragU u;
        if (q < 2) {
            const float* p = wu + (hc * 16 + c) * WW + q * 8;
            float4 f0 = *(const float4*)p;
            float4 f1 = *(const float4*)(p + 4);
            u.p2[0] = make_uint2(pk_bf16(f0.x, f0.y), pk_bf16(f0.z, f0.w));
            u.p2[1] = make_uint2(pk_bf16(f1.x, f1.y), pk_bf16(f1.z, f1.w));
        } else {
            u.p4 = make_uint4(0, 0, 0, 0);
        }
        a_wu[hc] = u.v;
    }

    // per-lane bias constants for this lane's w-slots (w = q*4+r)
    float4 bd4  = *(const float4*)(bd + q * 4);
    float4 kbu4 = *(const float4*)(kbu + q * 4);

    // ---- load X tile into C-layout accumulators: acc[hc][r] = X[row][hc*16+q*4+r]
    f32x4 acc[8];
    #pragma unroll
    for (int hc = 0; hc < 8; ++hc) {
        float4 f = *(const float4*)(x + row * HH + hc * 16 + q * 4);
        acc[hc][0] = f.x; acc[hc][1] = f.y; acc[hc][2] = f.z; acc[hc][3] = f.w;
    }

    const int xw = c * XRS + q * 2;  // + hc*8       (b64 writes)
    const int xr = c * XRS + q * 4;  // + kc*16      (2x b64 reads)
    const int rw = c * RRS + q * 2;
    const int rr = c * RRS + q * 4;

    for (int l = 0; l < LL; ++l) {
        // 1. spill Y (C-layout fp32) -> LDS as bf16, row-major [m=c][h]
        #pragma unroll
        for (int hc = 0; hc < 8; ++hc) {
            *(uint2*)&x_lds[xw + hc * 8] =
                make_uint2(pk_bf16(acc[hc][0], acc[hc][1]), pk_bf16(acc[hc][2], acc[hc][3]));
        }
        __syncthreads();   // B1: x RAW (cross-lane)

        // 2. down-proj: D[w][m] += wd[w][h] * Y[m][h], K=128
        f32x4 dreg = {0.f, 0.f, 0.f, 0.f};
        #pragma unroll
        for (int kc = 0; kc < 4; ++kc) {
            FragU u;
            u.p2[0] = *(const uint2*)&x_lds[xr + kc * 16];
            u.p2[1] = *(const uint2*)&x_lds[xr + kc * 16 + 2];
            dreg = __builtin_amdgcn_mfma_f32_16x16x32_bf16(a_wd[kc], u.v, dreg, 0, 0, 0);
        }

        // 3. epilogue: reg = relu(d + bd + l*kbu) * inst[l]   (w = q*4+r)
        float4 instv = *(const float4*)(&prog_lds[l * WW + q * 4]);
        float lf = (float)l;
        float r0 = fmaxf(dreg[0] + fmaf(lf, kbu4.x, bd4.x), 0.f) * instv.x;
        float r1 = fmaxf(dreg[1] + fmaf(lf, kbu4.y, bd4.y), 0.f) * instv.y;
        float r2 = fmaxf(dreg[2] + fmaf(lf, kbu4.z, bd4.z), 0.f) * instv.z;
        float r3 = fmaxf(dreg[3] + fmaf(lf, kbu4.w, bd4.w), 0.f) * instv.w;

        __syncthreads();   // B2: x WAR for next step, reg WAR from prev step
        *(uint2*)&reg_lds[rw] = make_uint2(pk_bf16(r0, r1), pk_bf16(r2, r3));
        __syncthreads();   // B3: reg RAW (cross-lane)

        // 4. up-proj: Y[m][h] += reg[m][w] * wu[h][w], K=16 (padded to 32 with zeros)
        FragU ur;
        ur.p4 = *(const uint4*)&reg_lds[rr];
        #pragma unroll
        for (int hc = 0; hc < 8; ++hc) {
            acc[hc] = __builtin_amdgcn_mfma_f32_16x16x32_bf16(a_wu[hc], ur.v, acc[hc], 0, 0, 0);
        }
    }

    // ---- store out = Y + 64*bu
    #pragma unroll
    for (int hc = 0; hc < 8; ++hc) {
        float4 bv = *(const float4*)(bu + hc * 16 + q * 4);
        float4 o;
        o.x = acc[hc][0] + 64.f * bv.x;
        o.y = acc[hc][1] + 64.f * bv.y;
        o.z = acc[hc][2] + 64.f * bv.z;
        o.w = acc[hc][3] + 64.f * bv.w;
        *(float4*)(out + row * HH + hc * 16 + q * 4) = o;
    }
}

extern "C" void kernel_launch(void* const* d_in, const int* in_sizes, int n_in,
                              void* d_out, int out_size, void* d_ws, size_t ws_size,
                              hipStream_t stream) {
    const float* x  = (const float*)d_in[0];
    const float* pr = (const float*)d_in[1];
    const float* wd = (const float*)d_in[2];
    const float* bd = (const float*)d_in[3];
    const float* wu = (const float*)d_in[4];
    const float* bu = (const float*)d_in[5];
    float* out = (float*)d_out;
    float* kbu = (float*)d_ws;   // 16 floats of scratch

    kbu_kernel<<<1, 64, 0, stream>>>(wd, bu, kbu);
    proc_kernel<<<NB / 16, 64, 0, stream>>>(x, pr, wd, bd, wu, bu, kbu, out);
}